// Round 2
// baseline (167.625 us; speedup 1.0000x reference)
//
#include <hip/hip_runtime.h>
#include <hip/hip_bf16.h>

// p1,p2 : (B=2, C=32, D=H=W=64) fp32. Pool 4x4x4 -> S=16, N = 8192 rows of C=32.
// loss = ||A Aᵀ - B Bᵀ||_F² / N² = (||AᵀA||² - 2||AᵀB||² + ||BᵀB||²) / N²
// with only 32x32 Grams. Verified exact (absmax 0.0) in round 1.

#define HW   4096      // 64*64
#define DHW  262144    // 64*64*64
#define NROW 8192
#define C    32

// ---------------------------------------------------------------------------
// Kernel 1: 4x4x4 avg-pool, streaming. One block per (arr, b, c, zp):
// 2048 blocks (8/CU = 100% occupancy), each reads a CONTIGUOUS 64 KiB slab
// (4 z-planes of one channel). Each float4 = one pooled-x window. At pass p,
// wave w's 64 lanes all belong to pooled row yp=(4p+w)&15, slice dz=(4p+w)>>4,
// with dy=lane>>4, xw=lane&15 -> register-accumulate over dz (4 indep chains),
// shfl_xor(16,32) over dy, 16-lane LDS store. No atomics.
// Output: unnormalized P row-major (N x 32), scattered dword stores (2 MB).
// ---------------------------------------------------------------------------
__global__ __launch_bounds__(256) void pool_kernel(
    const float* __restrict__ p1, const float* __restrict__ p2,
    float* __restrict__ Pa, float* __restrict__ Pb)
{
    const int bid = blockIdx.x;
    const int zp  = bid & 15;
    const int c   = (bid >> 4) & 31;
    const int b   = (bid >> 9) & 1;
    const int arr = bid >> 10;

    const float* __restrict__ src = arr ? p2 : p1;
    float* __restrict__ dst       = arr ? Pb : Pa;

    const float4* __restrict__ base = reinterpret_cast<const float4*>(
        src + (size_t)(b * C + c) * DHW + (size_t)(zp * 4) * HW);

    const int tid  = threadIdx.x;
    const int lane = tid & 63;
    const int w    = tid >> 6;

    __shared__ float pool[256];   // [yp*16 + xw]

    #pragma unroll
    for (int j = 0; j < 4; ++j) {
        float s = 0.f;
        #pragma unroll
        for (int dz = 0; dz < 4; ++dz) {
            const int p = j + 4 * dz;
            const float4 v = base[p * 256 + tid];
            s += (v.x + v.y) + (v.z + v.w);
        }
        // reduce over dy = lane>>4 (4 sub-rows of the y-window)
        s += __shfl_xor(s, 16);
        s += __shfl_xor(s, 32);
        const int yp = (4 * j + w) & 15;
        if (lane < 16) pool[yp * 16 + lane] = s * (1.0f / 64.0f);
    }
    __syncthreads();

    const int n = b * 4096 + zp * 256 + tid;   // row index
    dst[(size_t)n * C + c] = pool[tid];
}

// ---------------------------------------------------------------------------
// Kernel 2: fused row-normalize + three 32x32 Grams (Gaa, Gab, Gbb).
// 128 blocks x 256 threads, 64 rows/block. Staging float4 of thread t IS the
// (row=t>>3, cols=(t&7)*4) fragment -> row norm via dot + shfl_xor(1,2,4),
// scale in register, write LDS. Then 12-accumulator register Gram, one
// atomicAdd set per thread at the end.
// ---------------------------------------------------------------------------
__global__ __launch_bounds__(256) void gram_kernel(
    const float* __restrict__ Pa, const float* __restrict__ Pb,
    float* __restrict__ G)   // [0..1023]=Gaa, [1024..2047]=Gab, [2048..3071]=Gbb
{
    const int tid = threadIdx.x;
    const int k  = tid >> 3;          // 0..31
    const int l4 = (tid & 7) * 4;     // 0,4,...,28

    __shared__ float As[32 * C];
    __shared__ float Bs[32 * C];

    float gaa[4] = {0.f, 0.f, 0.f, 0.f};
    float gab[4] = {0.f, 0.f, 0.f, 0.f};
    float gbb[4] = {0.f, 0.f, 0.f, 0.f};

    const int row0 = blockIdx.x * 64;
    for (int t = 0; t < 2; ++t) {
        const int r = row0 + t * 32;
        float4 va = reinterpret_cast<const float4*>(Pa + (size_t)r * C)[tid];
        float4 vb = reinterpret_cast<const float4*>(Pb + (size_t)r * C)[tid];

        // row sum-of-squares across the 8 lanes sharing row k = tid>>3
        float ssa = va.x*va.x + va.y*va.y + va.z*va.z + va.w*va.w;
        float ssb = vb.x*vb.x + vb.y*vb.y + vb.z*vb.z + vb.w*vb.w;
        ssa += __shfl_xor(ssa, 1); ssa += __shfl_xor(ssa, 2); ssa += __shfl_xor(ssa, 4);
        ssb += __shfl_xor(ssb, 1); ssb += __shfl_xor(ssb, 2); ssb += __shfl_xor(ssb, 4);
        const float inva = 1.0f / fmaxf(sqrtf(ssa), 1e-8f);
        const float invb = 1.0f / fmaxf(sqrtf(ssb), 1e-8f);
        va.x *= inva; va.y *= inva; va.z *= inva; va.w *= inva;
        vb.x *= invb; vb.y *= invb; vb.z *= invb; vb.w *= invb;

        reinterpret_cast<float4*>(As)[tid] = va;
        reinterpret_cast<float4*>(Bs)[tid] = vb;
        __syncthreads();

        #pragma unroll
        for (int i = 0; i < 32; ++i) {
            const float a_k = As[i * C + k];
            const float b_k = Bs[i * C + k];
            const float4 a_l = *reinterpret_cast<const float4*>(&As[i * C + l4]);
            const float4 b_l = *reinterpret_cast<const float4*>(&Bs[i * C + l4]);
            gaa[0] += a_k * a_l.x;  gaa[1] += a_k * a_l.y;
            gaa[2] += a_k * a_l.z;  gaa[3] += a_k * a_l.w;
            gab[0] += a_k * b_l.x;  gab[1] += a_k * b_l.y;
            gab[2] += a_k * b_l.z;  gab[3] += a_k * b_l.w;
            gbb[0] += b_k * b_l.x;  gbb[1] += b_k * b_l.y;
            gbb[2] += b_k * b_l.z;  gbb[3] += b_k * b_l.w;
        }
        __syncthreads();
    }

    float* Gaa = G;
    float* Gab = G + 1024;
    float* Gbb = G + 2048;
    #pragma unroll
    for (int j = 0; j < 4; ++j) {
        atomicAdd(&Gaa[k * C + l4 + j], gaa[j]);
        atomicAdd(&Gab[k * C + l4 + j], gab[j]);
        atomicAdd(&Gbb[k * C + l4 + j], gbb[j]);
    }
}

// ---------------------------------------------------------------------------
// Kernel 3: loss = (sum Gaa² - 2 sum Gab² + sum Gbb²) / N²
// ---------------------------------------------------------------------------
__global__ __launch_bounds__(1024) void finalize_kernel(
    const float* __restrict__ G, float* __restrict__ out)
{
    const int t = threadIdx.x;
    const float gaa = G[t];
    const float gab = G[1024 + t];
    const float gbb = G[2048 + t];
    float v = gaa * gaa + gbb * gbb - 2.f * gab * gab;

    __shared__ float red[16];
    #pragma unroll
    for (int off = 32; off > 0; off >>= 1) v += __shfl_down(v, off);
    if ((t & 63) == 0) red[t >> 6] = v;
    __syncthreads();
    if (t < 16) {
        float w = red[t];
        #pragma unroll
        for (int off = 8; off > 0; off >>= 1) w += __shfl_down(w, off);
        if (t == 0) out[0] = w / ((float)NROW * (float)NROW);
    }
}

extern "C" void kernel_launch(void* const* d_in, const int* in_sizes, int n_in,
                              void* d_out, int out_size, void* d_ws, size_t ws_size,
                              hipStream_t stream) {
    const float* p1 = (const float*)d_in[0];
    const float* p2 = (const float*)d_in[1];
    float* out = (float*)d_out;

    float* Pa = (float*)d_ws;                    // 8192*32 floats = 1 MiB (unnormalized)
    float* Pb = Pa + (size_t)NROW * C;           // 1 MiB
    float* G  = Pb + (size_t)NROW * C;           // 3*1024 floats = 12 KiB

    hipMemsetAsync(G, 0, 3 * 1024 * sizeof(float), stream);

    pool_kernel<<<2048, 256, 0, stream>>>(p1, p2, Pa, Pb);
    gram_kernel<<<128, 256, 0, stream>>>(Pa, Pb, G);
    finalize_kernel<<<1, 1024, 0, stream>>>(G, out);
}